// Round 2
// baseline (464.452 us; speedup 1.0000x reference)
//
#include <hip/hip_runtime.h>

#define NPTS 4096
#define NBATCH 4
#define HDIM 192
#define CDIM 384

typedef _Float16 f16x8 __attribute__((ext_vector_type(8)));
typedef float f32x4 __attribute__((ext_vector_type(4)));

// ---------------- K0: W2 [192][384] f32 -> W2T [384][192] f16 ----------------
__global__ __launch_bounds__(256) void prep_w2(const float* __restrict__ W2,
                                               _Float16* __restrict__ W2T) {
  int i = blockIdx.x * 256 + threadIdx.x;
  if (i < HDIM * CDIM) {
    int h = i / CDIM, c = i % CDIM;
    W2T[c * HDIM + h] = (_Float16)W2[i];
  }
}

// ---------------- K1: KNN via filter-then-prune ----------------
// 512 blocks x 512 thr. Block: 32 queries. Lane = (query ql=lane&31, half h=lane>>5).
// Chunk per lane: c = wv*2+h in [0,16), candidates [c*256,(c+1)*256).
// Main loop: distance + threshold filter + u16 append to per-lane LDS stack.
// Prune (rare): sorted-insert survivors into per-lane top-16 (stable: ascending j, strict <).
// Merge: 16 sorted lists -> 4 (stage1, 128 thr) -> 1 (stage2, 32 thr), strict < prefers lower chunk.
#define SCAP 30
#define FINF 3.4e38f

__global__ __launch_bounds__(512, 4) void knn_kernel(const float* __restrict__ pts,
                                                     int* __restrict__ idx_out) {
  __shared__ float smem[12352];    // points 12288 f32; later md f32[8223] + mi u16[8223] @8224
  __shared__ float sstk_f[7680];   // stacks u16[512*30]; later od f32[2079] + oi u16[2079] @2080
  unsigned short* sstk = (unsigned short*)sstk_f;

  float* spx = smem;
  float* spy = smem + 4096;
  float* spz = smem + 8192;

  const int t  = threadIdx.x;
  const int b  = blockIdx.x >> 7;           // 128 blocks per batch
  const int qb = (blockIdx.x & 127) << 5;   // 32 queries per block
  const float* P = pts + (size_t)b * NPTS * 3;

  for (int i = t; i < NPTS; i += 512) {
    spx[i] = P[3 * i + 0];
    spy[i] = P[3 * i + 1];
    spz[i] = P[3 * i + 2];
  }
  __syncthreads();

  const int lane  = t & 63;
  const int ql    = lane & 31;
  const int q     = qb + ql;
  const int cid   = (t >> 5) & 15;          // chunk id 0..15
  const int cbase = cid << 8;
  const float qx = spx[q], qy = spy[q], qz = spz[q];

  float dl[16];
  int   il[16];
#pragma unroll
  for (int i = 0; i < 16; ++i) { dl[i] = FINF; il[i] = 0; }
  float thr = FINF;
  int   cnt = 0;
  const int sbase = t * SCAP;

  auto prune = [&]() {
    int mc = cnt;
#pragma unroll
    for (int s = 32; s; s >>= 1) { int o = __shfl_xor(mc, s); mc = mc > o ? mc : o; }
    mc = __builtin_amdgcn_readfirstlane(mc);
    for (int e = 0; e < mc; ++e) {
      const int j = sstk[sbase + e] & 4095;      // clamp garbage for inactive lanes
      const float dx = qx - spx[j];
      const float dy = qy - spy[j];
      const float dz = qz - spz[j];
      const float d = __fadd_rn(__fadd_rn(__fmul_rn(dx, dx), __fmul_rn(dy, dy)),
                                __fmul_rn(dz, dz));
      const float v = (e < cnt && d < dl[15]) ? d : FINF;   // identity insert otherwise
      bool cc[16];
#pragma unroll
      for (int i = 0; i < 16; ++i) cc[i] = v < dl[i];
#pragma unroll
      for (int i = 15; i >= 1; --i) {
        dl[i] = cc[i] ? (cc[i - 1] ? dl[i - 1] : v) : dl[i];
        il[i] = cc[i] ? (cc[i - 1] ? il[i - 1] : j) : il[i];
      }
      dl[0] = cc[0] ? v : dl[0];
      il[0] = cc[0] ? j : il[0];
    }
    cnt = 0;
    thr = dl[15];
  };

  for (int jt = 0; jt < 256; jt += 8) {
#pragma unroll
    for (int u = 0; u < 8; ++u) {
      const int j = cbase + jt + u;
      const float dx = qx - spx[j];
      const float dy = qy - spy[j];
      const float dz = qz - spz[j];
      // EXACT match to numpy/jax: ((dx*dx + dy*dy) + dz*dz), f32, no FMA contraction
      const float d = __fadd_rn(__fadd_rn(__fmul_rn(dx, dx), __fmul_rn(dy, dy)),
                                __fmul_rn(dz, dz));
      if (d < thr) { sstk[sbase + cnt] = (unsigned short)j; ++cnt; }
    }
    if (__any(cnt >= SCAP - 8)) prune();
  }
  prune();  // fold remaining stack entries

  __syncthreads();  // points + stacks now dead

  // write per-lane sorted lists: md stride 257/query (bank-spread), 16 lists of 16 each
  float*          md = smem;
  unsigned short* mi = (unsigned short*)(smem + 8224);
  const int lbase = ql * 257 + cid * 16;
#pragma unroll
  for (int i = 0; i < 16; ++i) {
    md[lbase + i] = dl[i];
    mi[lbase + i] = (unsigned short)il[i];
  }
  __syncthreads();

  // stage 1: 16 lists -> 4 (each thread 4-way merges lists 4g..4g+3), 128 threads
  float*          od = sstk_f;
  unsigned short* oi = (unsigned short*)(sstk_f + 2080);
  if (t < 128) {
    const int mq = t >> 2, g = t & 3;
    const int base = mq * 257 + g * 64;
    int p0 = 0, p1 = 0, p2 = 0, p3 = 0;
    const int ob = mq * 65 + g * 16;
    for (int r = 0; r < 16; ++r) {
      const float d0 = md[base + p0];
      const float d1 = md[base + 16 + p1];
      const float d2 = md[base + 32 + p2];
      const float d3 = md[base + 48 + p3];
      int bw = 0; float bd = d0;
      if (d1 < bd) { bd = d1; bw = 1; }
      if (d2 < bd) { bd = d2; bw = 2; }
      if (d3 < bd) { bd = d3; bw = 3; }
      const unsigned short bi = (bw == 0) ? mi[base + p0]
                              : (bw == 1) ? mi[base + 16 + p1]
                              : (bw == 2) ? mi[base + 32 + p2]
                                          : mi[base + 48 + p3];
      od[ob + r] = bd;
      oi[ob + r] = bi;
      p0 += (bw == 0); p1 += (bw == 1); p2 += (bw == 2); p3 += (bw == 3);
    }
  }
  __syncthreads();

  // stage 2: 4 lists -> 1, 32 threads, write global
  if (t < 32) {
    const int base = t * 65;
    int p0 = 0, p1 = 0, p2 = 0, p3 = 0;
    int* op = idx_out + (((size_t)b * NPTS + qb + t) << 4);
    for (int r = 0; r < 16; ++r) {
      const float d0 = od[base + p0];
      const float d1 = od[base + 16 + p1];
      const float d2 = od[base + 32 + p2];
      const float d3 = od[base + 48 + p3];
      int bw = 0; float bd = d0;
      if (d1 < bd) { bd = d1; bw = 1; }
      if (d2 < bd) { bd = d2; bw = 2; }
      if (d3 < bd) { bd = d3; bw = 3; }
      const unsigned short bi = (bw == 0) ? oi[base + p0]
                              : (bw == 1) ? oi[base + 16 + p1]
                              : (bw == 2) ? oi[base + 32 + p2]
                                          : oi[base + 48 + p3];
      op[r] = (int)bi;
      p0 += (bw == 0); p1 += (bw == 1); p2 += (bw == 2); p3 += (bw == 3);
    }
  }
}

// ---------------- K2: fused layer1(swish, fp32) -> f16 MFMA layer2 -> maxpool ----------------
__global__ __launch_bounds__(512) void mlp_kernel(const float* __restrict__ pts,
                                                  const int* __restrict__ idx,
                                                  const float* __restrict__ W1,
                                                  const float* __restrict__ b1,
                                                  const _Float16* __restrict__ W2T,
                                                  const float* __restrict__ b2,
                                                  float* __restrict__ out) {
  __shared__ _Float16 sA[128 * 200];       // 51.2 KB

  const int bid = blockIdx.x;
  const int b   = bid >> 9;
  const int qb  = (bid & 511) << 3;
  const float* P = pts + (size_t)b * NPTS * 3;
  const int t = threadIdx.x;

  {
    const int row = t >> 2;
    const int sub = t & 3;
    const int ql  = row >> 4;
    const int kk  = row & 15;
    const int qq  = qb + ql;
    const int nb  = idx[(((size_t)b * NPTS + qq) << 4) + kk];
    const float pqx = P[qq * 3 + 0], pqy = P[qq * 3 + 1], pqz = P[qq * 3 + 2];
    const float f0 = P[nb * 3 + 0] - pqx;
    const float f1 = P[nb * 3 + 1] - pqy;
    const float f2 = P[nb * 3 + 2] - pqz;
    const int h0 = sub * 48;
#pragma unroll 4
    for (int hh = 0; hh < 48; ++hh) {
      const int h = h0 + hh;
      float a = b1[h] + f0 * W1[h]             + f1 * W1[HDIM + h]      + f2 * W1[2 * HDIM + h]
                      + pqx * W1[3 * HDIM + h] + pqy * W1[4 * HDIM + h] + pqz * W1[5 * HDIM + h];
      const float s = a * (1.0f / (1.0f + __expf(-a)));
      sA[row * 200 + h] = (_Float16)s;
    }
  }
  __syncthreads();

  const int lane = t & 63;
  const int wv   = t >> 6;
  const int ln15 = lane & 15;
  const int kgr  = lane >> 4;

  for (int ct = wv; ct < 24; ct += 8) {
    f32x4 acc[8];
#pragma unroll
    for (int qi = 0; qi < 8; ++qi)
#pragma unroll
      for (int e = 0; e < 4; ++e) acc[qi][e] = 0.0f;

    const int c = ct * 16 + ln15;
#pragma unroll
    for (int kt = 0; kt < 6; ++kt) {
      const int k0 = kt * 32 + kgr * 8;
      const f16x8 bf = *(const f16x8*)(W2T + (size_t)c * HDIM + k0);
#pragma unroll
      for (int qi = 0; qi < 8; ++qi) {
        const f16x8 af = *(const f16x8*)(sA + (qi * 16 + ln15) * 200 + k0);
        acc[qi] = __builtin_amdgcn_mfma_f32_16x16x32_f16(af, bf, acc[qi], 0, 0, 0);
      }
    }

    const float bb = b2[c];
#pragma unroll
    for (int qi = 0; qi < 8; ++qi) {
      float m = fmaxf(fmaxf(acc[qi][0], acc[qi][1]), fmaxf(acc[qi][2], acc[qi][3]));
      m = fmaxf(m, __shfl_xor(m, 16));
      m = fmaxf(m, __shfl_xor(m, 32));
      if (lane < 16)
        out[((size_t)b * NPTS + qb + qi) * CDIM + c] = m + bb;
    }
  }
}

extern "C" void kernel_launch(void* const* d_in, const int* in_sizes, int n_in,
                              void* d_out, int out_size, void* d_ws, size_t ws_size,
                              hipStream_t stream) {
  const float* point = (const float*)d_in[0];
  const float* W1    = (const float*)d_in[1];
  const float* b1    = (const float*)d_in[2];
  const float* W2    = (const float*)d_in[3];
  const float* b2    = (const float*)d_in[4];

  int*      idx_ws = (int*)d_ws;
  _Float16* W2T    = (_Float16*)((char*)d_ws + (1 << 20));

  prep_w2<<<(HDIM * CDIM + 255) / 256, 256, 0, stream>>>(W2, W2T);
  knn_kernel<<<512, 512, 0, stream>>>(point, idx_ws);
  mlp_kernel<<<NBATCH * 512, 512, 0, stream>>>(point, idx_ws, W1, b1, W2T, b2, (float*)d_out);
}

// Round 3
// 259.599 us; speedup vs baseline: 1.7891x; 1.7891x over previous
//
#include <hip/hip_runtime.h>

#define NPTS 4096
#define NBATCH 4
#define HDIM 192
#define CDIM 384

typedef _Float16 f16x8 __attribute__((ext_vector_type(8)));
typedef float f32x4 __attribute__((ext_vector_type(4)));

// ---------------- K0: W2 [192][384] f32 -> W2T [384][192] f16 ----------------
__global__ __launch_bounds__(256) void prep_w2(const float* __restrict__ W2,
                                               _Float16* __restrict__ W2T) {
  int i = blockIdx.x * 256 + threadIdx.x;
  if (i < HDIM * CDIM) {
    int h = i / CDIM, c = i % CDIM;
    W2T[c * HDIM + h] = (_Float16)W2[i];
  }
}

// ---------------- K1: KNN via filter-then-prune ----------------
// 512 blocks x 512 thr. Block: 32 queries. Lane = (query ql=lane&31, half=lane>>5).
// Chunk per lane: cid = (t>>5)&15, candidates [cid*256,(cid+1)*256).
// Main loop: distance + threshold filter + u16 append to per-lane LDS stack.
// Prune (rare, MACRO-inlined so dl/il are never address-taken -> stay in VGPRs):
// sorted-insert survivors into per-lane top-16 (stable: ascending j, strict <).
// Merge: 16 sorted lists -> 4 -> 1, strict < prefers lower chunk id = lower index.
#define SCAP 30
#define FINF 3.4e38f

// NOTE: macro, not lambda — a [&] lambda address-takes dl/il and SROA fails,
// spilling both arrays to scratch (R2: WRITE_SIZE 326MB, +15% runtime).
#define PRUNE()                                                                      \
  do {                                                                               \
    int mc = cnt;                                                                    \
    _Pragma("unroll")                                                                \
    for (int s = 32; s; s >>= 1) { int o = __shfl_xor(mc, s); mc = mc > o ? mc : o; }\
    mc = __builtin_amdgcn_readfirstlane(mc);                                         \
    for (int e = 0; e < mc; ++e) {                                                   \
      const int j = sstk[sbase + e] & 4095;                                          \
      const float dx = qx - spx[j];                                                  \
      const float dy = qy - spy[j];                                                  \
      const float dz = qz - spz[j];                                                  \
      const float d = __fadd_rn(__fadd_rn(__fmul_rn(dx, dx), __fmul_rn(dy, dy)),     \
                                __fmul_rn(dz, dz));                                  \
      const float v = (e < cnt && d < dl[15]) ? d : FINF;                            \
      bool cc[16];                                                                   \
      _Pragma("unroll")                                                              \
      for (int i = 0; i < 16; ++i) cc[i] = v < dl[i];                                \
      _Pragma("unroll")                                                              \
      for (int i = 15; i >= 1; --i) {                                                \
        dl[i] = cc[i] ? (cc[i - 1] ? dl[i - 1] : v) : dl[i];                         \
        il[i] = cc[i] ? (cc[i - 1] ? il[i - 1] : j) : il[i];                         \
      }                                                                              \
      dl[0] = cc[0] ? v : dl[0];                                                     \
      il[0] = cc[0] ? j : il[0];                                                     \
    }                                                                                \
    cnt = 0;                                                                         \
    thr = dl[15];                                                                    \
  } while (0)

__global__ __launch_bounds__(512) void knn_kernel(const float* __restrict__ pts,
                                                  int* __restrict__ idx_out) {
  __shared__ float smem[12352];    // points 12288 f32; later md f32[8223] + mi u16 @8224
  __shared__ float sstk_f[7680];   // stacks u16[512*30]; later od f32[2079] + oi u16 @2080
  unsigned short* sstk = (unsigned short*)sstk_f;

  float* spx = smem;
  float* spy = smem + 4096;
  float* spz = smem + 8192;

  const int t  = threadIdx.x;
  const int b  = blockIdx.x >> 7;           // 128 blocks per batch
  const int qb = (blockIdx.x & 127) << 5;   // 32 queries per block
  const float* P = pts + (size_t)b * NPTS * 3;

  for (int i = t; i < NPTS; i += 512) {
    spx[i] = P[3 * i + 0];
    spy[i] = P[3 * i + 1];
    spz[i] = P[3 * i + 2];
  }
  __syncthreads();

  const int ql    = t & 31;
  const int q     = qb + ql;
  const int cid   = (t >> 5) & 15;          // chunk id 0..15
  const int cbase = cid << 8;
  const float qx = spx[q], qy = spy[q], qz = spz[q];

  float dl[16];
  int   il[16];
#pragma unroll
  for (int i = 0; i < 16; ++i) { dl[i] = FINF; il[i] = 0; }
  float thr = FINF;
  int   cnt = 0;
  const int sbase = t * SCAP;

  for (int jt = 0; jt < 256; jt += 8) {
#pragma unroll
    for (int u = 0; u < 8; ++u) {
      const int j = cbase + jt + u;
      const float dx = qx - spx[j];
      const float dy = qy - spy[j];
      const float dz = qz - spz[j];
      // EXACT match to numpy/jax: ((dx*dx + dy*dy) + dz*dz), f32, no FMA contraction
      const float d = __fadd_rn(__fadd_rn(__fmul_rn(dx, dx), __fmul_rn(dy, dy)),
                                __fmul_rn(dz, dz));
      if (d < thr) { sstk[sbase + cnt] = (unsigned short)j; ++cnt; }
    }
    if (__any(cnt >= SCAP - 8)) PRUNE();
  }
  PRUNE();  // fold remaining stack entries

  __syncthreads();  // points + stacks now dead

  // write per-lane sorted lists: md stride 257/query (bank-spread), 16 lists of 16 each
  float*          md = smem;
  unsigned short* mi = (unsigned short*)(smem + 8224);
  const int lbase = ql * 257 + cid * 16;
#pragma unroll
  for (int i = 0; i < 16; ++i) {
    md[lbase + i] = dl[i];
    mi[lbase + i] = (unsigned short)il[i];
  }
  __syncthreads();

  // stage 1: 16 lists -> 4 (each thread 4-way merges lists 4g..4g+3), 128 threads
  float*          od = sstk_f;
  unsigned short* oi = (unsigned short*)(sstk_f + 2080);
  if (t < 128) {
    const int mq = t >> 2, g = t & 3;
    const int base = mq * 257 + g * 64;
    int p0 = 0, p1 = 0, p2 = 0, p3 = 0;
    const int ob = mq * 65 + g * 16;
    for (int r = 0; r < 16; ++r) {
      const float d0 = md[base + p0];
      const float d1 = md[base + 16 + p1];
      const float d2 = md[base + 32 + p2];
      const float d3 = md[base + 48 + p3];
      int bw = 0; float bd = d0;
      if (d1 < bd) { bd = d1; bw = 1; }
      if (d2 < bd) { bd = d2; bw = 2; }
      if (d3 < bd) { bd = d3; bw = 3; }
      const unsigned short bi = (bw == 0) ? mi[base + p0]
                              : (bw == 1) ? mi[base + 16 + p1]
                              : (bw == 2) ? mi[base + 32 + p2]
                                          : mi[base + 48 + p3];
      od[ob + r] = bd;
      oi[ob + r] = bi;
      p0 += (bw == 0); p1 += (bw == 1); p2 += (bw == 2); p3 += (bw == 3);
    }
  }
  __syncthreads();

  // stage 2: 4 lists -> 1, 32 threads, write global
  if (t < 32) {
    const int base = t * 65;
    int p0 = 0, p1 = 0, p2 = 0, p3 = 0;
    int* op = idx_out + (((size_t)b * NPTS + qb + t) << 4);
    for (int r = 0; r < 16; ++r) {
      const float d0 = od[base + p0];
      const float d1 = od[base + 16 + p1];
      const float d2 = od[base + 32 + p2];
      const float d3 = od[base + 48 + p3];
      int bw = 0; float bd = d0;
      if (d1 < bd) { bd = d1; bw = 1; }
      if (d2 < bd) { bd = d2; bw = 2; }
      if (d3 < bd) { bd = d3; bw = 3; }
      const unsigned short bi = (bw == 0) ? oi[base + p0]
                              : (bw == 1) ? oi[base + 16 + p1]
                              : (bw == 2) ? oi[base + 32 + p2]
                                          : oi[base + 48 + p3];
      op[r] = (int)bi;
      p0 += (bw == 0); p1 += (bw == 1); p2 += (bw == 2); p3 += (bw == 3);
    }
  }
}

// ---------------- K2: fused layer1(swish, fp32) -> f16 MFMA layer2 -> maxpool ----------------
__global__ __launch_bounds__(512) void mlp_kernel(const float* __restrict__ pts,
                                                  const int* __restrict__ idx,
                                                  const float* __restrict__ W1,
                                                  const float* __restrict__ b1,
                                                  const _Float16* __restrict__ W2T,
                                                  const float* __restrict__ b2,
                                                  float* __restrict__ out) {
  __shared__ _Float16 sA[128 * 200];       // 51.2 KB

  const int bid = blockIdx.x;
  const int b   = bid >> 9;
  const int qb  = (bid & 511) << 3;
  const float* P = pts + (size_t)b * NPTS * 3;
  const int t = threadIdx.x;

  {
    const int row = t >> 2;
    const int sub = t & 3;
    const int ql  = row >> 4;
    const int kk  = row & 15;
    const int qq  = qb + ql;
    const int nb  = idx[(((size_t)b * NPTS + qq) << 4) + kk];
    const float pqx = P[qq * 3 + 0], pqy = P[qq * 3 + 1], pqz = P[qq * 3 + 2];
    const float f0 = P[nb * 3 + 0] - pqx;
    const float f1 = P[nb * 3 + 1] - pqy;
    const float f2 = P[nb * 3 + 2] - pqz;
    const int h0 = sub * 48;
#pragma unroll 4
    for (int hh = 0; hh < 48; ++hh) {
      const int h = h0 + hh;
      float a = b1[h] + f0 * W1[h]             + f1 * W1[HDIM + h]      + f2 * W1[2 * HDIM + h]
                      + pqx * W1[3 * HDIM + h] + pqy * W1[4 * HDIM + h] + pqz * W1[5 * HDIM + h];
      const float s = a * (1.0f / (1.0f + __expf(-a)));
      sA[row * 200 + h] = (_Float16)s;
    }
  }
  __syncthreads();

  const int lane = t & 63;
  const int wv   = t >> 6;
  const int ln15 = lane & 15;
  const int kgr  = lane >> 4;

  for (int ct = wv; ct < 24; ct += 8) {
    f32x4 acc[8];
#pragma unroll
    for (int qi = 0; qi < 8; ++qi)
#pragma unroll
      for (int e = 0; e < 4; ++e) acc[qi][e] = 0.0f;

    const int c = ct * 16 + ln15;
#pragma unroll
    for (int kt = 0; kt < 6; ++kt) {
      const int k0 = kt * 32 + kgr * 8;
      const f16x8 bf = *(const f16x8*)(W2T + (size_t)c * HDIM + k0);
#pragma unroll
      for (int qi = 0; qi < 8; ++qi) {
        const f16x8 af = *(const f16x8*)(sA + (qi * 16 + ln15) * 200 + k0);
        acc[qi] = __builtin_amdgcn_mfma_f32_16x16x32_f16(af, bf, acc[qi], 0, 0, 0);
      }
    }

    const float bb = b2[c];
#pragma unroll
    for (int qi = 0; qi < 8; ++qi) {
      float m = fmaxf(fmaxf(acc[qi][0], acc[qi][1]), fmaxf(acc[qi][2], acc[qi][3]));
      m = fmaxf(m, __shfl_xor(m, 16));
      m = fmaxf(m, __shfl_xor(m, 32));
      if (lane < 16)
        out[((size_t)b * NPTS + qb + qi) * CDIM + c] = m + bb;
    }
  }
}

extern "C" void kernel_launch(void* const* d_in, const int* in_sizes, int n_in,
                              void* d_out, int out_size, void* d_ws, size_t ws_size,
                              hipStream_t stream) {
  const float* point = (const float*)d_in[0];
  const float* W1    = (const float*)d_in[1];
  const float* b1    = (const float*)d_in[2];
  const float* W2    = (const float*)d_in[3];
  const float* b2    = (const float*)d_in[4];

  int*      idx_ws = (int*)d_ws;
  _Float16* W2T    = (_Float16*)((char*)d_ws + (1 << 20));

  prep_w2<<<(HDIM * CDIM + 255) / 256, 256, 0, stream>>>(W2, W2T);
  knn_kernel<<<512, 512, 0, stream>>>(point, idx_ws);
  mlp_kernel<<<NBATCH * 512, 512, 0, stream>>>(point, idx_ws, W1, b1, W2T, b2, (float*)d_out);
}

// Round 4
// 215.663 us; speedup vs baseline: 2.1536x; 1.2037x over previous
//
#include <hip/hip_runtime.h>

#define NPTS 4096
#define NBATCH 4
#define HDIM 192
#define CDIM 384

typedef _Float16 f16x8 __attribute__((ext_vector_type(8)));
typedef float f32x4 __attribute__((ext_vector_type(4)));

// ---------------- K0: W2 [192][384] f32 -> W2T [384][192] f16 ----------------
__global__ __launch_bounds__(256) void prep_w2(const float* __restrict__ W2,
                                               _Float16* __restrict__ W2T) {
  int i = blockIdx.x * 256 + threadIdx.x;
  if (i < HDIM * CDIM) {
    int h = i / CDIM, c = i % CDIM;
    W2T[c * HDIM + h] = (_Float16)W2[i];
  }
}

// ---------------- K1: KNN via filter-then-prune ----------------
// 512 blocks x 512 thr. Block: 32 queries. Lane: (ql=t&31, cid=(t>>5)&15).
// Candidate loads vectorized: ds_read_b128 x6 per 8 candidates (was 24x b32).
#define SCAP 30
#define FINF 3.4e38f

// macro, not lambda: a [&] lambda address-takes dl/il -> scratch spill (R2 lesson)
#define PRUNE()                                                                      \
  do {                                                                               \
    int mc = cnt;                                                                    \
    _Pragma("unroll")                                                                \
    for (int s = 32; s; s >>= 1) { int o = __shfl_xor(mc, s); mc = mc > o ? mc : o; }\
    mc = __builtin_amdgcn_readfirstlane(mc);                                         \
    for (int e = 0; e < mc; ++e) {                                                   \
      const int j = sstk[sbase + e] & 4095;                                          \
      const float dx = qx - spx[j];                                                  \
      const float dy = qy - spy[j];                                                  \
      const float dz = qz - spz[j];                                                  \
      const float d = __fadd_rn(__fadd_rn(__fmul_rn(dx, dx), __fmul_rn(dy, dy)),     \
                                __fmul_rn(dz, dz));                                  \
      const float v = (e < cnt && d < dl[15]) ? d : FINF;                            \
      bool cc[16];                                                                   \
      _Pragma("unroll")                                                              \
      for (int i = 0; i < 16; ++i) cc[i] = v < dl[i];                                \
      _Pragma("unroll")                                                              \
      for (int i = 15; i >= 1; --i) {                                                \
        dl[i] = cc[i] ? (cc[i - 1] ? dl[i - 1] : v) : dl[i];                         \
        il[i] = cc[i] ? (cc[i - 1] ? il[i - 1] : j) : il[i];                         \
      }                                                                              \
      dl[0] = cc[0] ? v : dl[0];                                                     \
      il[0] = cc[0] ? j : il[0];                                                     \
    }                                                                                \
    cnt = 0;                                                                         \
    thr = dl[15];                                                                    \
  } while (0)

__global__ __launch_bounds__(512) void knn_kernel(const float* __restrict__ pts,
                                                  int* __restrict__ idx_out) {
  __shared__ float smem[12352];    // points 12288 f32; later md f32 + mi u16 @8224
  __shared__ float sstk_f[7680];   // stacks u16[512*30]; later od f32 + oi u16 @2080
  unsigned short* sstk = (unsigned short*)sstk_f;

  float* spx = smem;
  float* spy = smem + 4096;
  float* spz = smem + 8192;

  const int t  = threadIdx.x;
  const int b  = blockIdx.x >> 7;
  const int qb = (blockIdx.x & 127) << 5;
  const float* P = pts + (size_t)b * NPTS * 3;

  for (int i = t; i < NPTS; i += 512) {
    spx[i] = P[3 * i + 0];
    spy[i] = P[3 * i + 1];
    spz[i] = P[3 * i + 2];
  }
  __syncthreads();

  const int ql    = t & 31;
  const int q     = qb + ql;
  const int cid   = (t >> 5) & 15;
  const int cbase = cid << 8;
  const float qx = spx[q], qy = spy[q], qz = spz[q];

  float dl[16];
  int   il[16];
#pragma unroll
  for (int i = 0; i < 16; ++i) { dl[i] = FINF; il[i] = 0; }
  float thr = FINF;
  int   cnt = 0;
  const int sbase = t * SCAP;

  for (int jt = 0; jt < 256; jt += 8) {
    const int jb = cbase + jt;
    const f32x4 x0 = *(const f32x4*)(spx + jb);
    const f32x4 x1 = *(const f32x4*)(spx + jb + 4);
    const f32x4 y0 = *(const f32x4*)(spy + jb);
    const f32x4 y1 = *(const f32x4*)(spy + jb + 4);
    const f32x4 z0 = *(const f32x4*)(spz + jb);
    const f32x4 z1 = *(const f32x4*)(spz + jb + 4);
#pragma unroll
    for (int u = 0; u < 8; ++u) {
      const float px = (u < 4) ? x0[u & 3] : x1[u & 3];
      const float py = (u < 4) ? y0[u & 3] : y1[u & 3];
      const float pz = (u < 4) ? z0[u & 3] : z1[u & 3];
      const float dx = qx - px;
      const float dy = qy - py;
      const float dz = qz - pz;
      // EXACT match to numpy/jax: ((dx*dx + dy*dy) + dz*dz), f32, no FMA contraction
      const float d = __fadd_rn(__fadd_rn(__fmul_rn(dx, dx), __fmul_rn(dy, dy)),
                                __fmul_rn(dz, dz));
      if (d < thr) { sstk[sbase + cnt] = (unsigned short)(jb + u); ++cnt; }
    }
    if (__any(cnt >= SCAP - 8)) PRUNE();
  }
  PRUNE();

  __syncthreads();  // points + stacks now dead

  float*          md = smem;
  unsigned short* mi = (unsigned short*)(smem + 8224);
  const int lbase = ql * 257 + cid * 16;
#pragma unroll
  for (int i = 0; i < 16; ++i) {
    md[lbase + i] = dl[i];
    mi[lbase + i] = (unsigned short)il[i];
  }
  __syncthreads();

  float*          od = sstk_f;
  unsigned short* oi = (unsigned short*)(sstk_f + 2080);
  if (t < 128) {
    const int mq = t >> 2, g = t & 3;
    const int base = mq * 257 + g * 64;
    int p0 = 0, p1 = 0, p2 = 0, p3 = 0;
    const int ob = mq * 65 + g * 16;
    for (int r = 0; r < 16; ++r) {
      const float d0 = md[base + p0];
      const float d1 = md[base + 16 + p1];
      const float d2 = md[base + 32 + p2];
      const float d3 = md[base + 48 + p3];
      int bw = 0; float bd = d0;
      if (d1 < bd) { bd = d1; bw = 1; }
      if (d2 < bd) { bd = d2; bw = 2; }
      if (d3 < bd) { bd = d3; bw = 3; }
      const unsigned short bi = (bw == 0) ? mi[base + p0]
                              : (bw == 1) ? mi[base + 16 + p1]
                              : (bw == 2) ? mi[base + 32 + p2]
                                          : mi[base + 48 + p3];
      od[ob + r] = bd;
      oi[ob + r] = bi;
      p0 += (bw == 0); p1 += (bw == 1); p2 += (bw == 2); p3 += (bw == 3);
    }
  }
  __syncthreads();

  if (t < 32) {
    const int base = t * 65;
    int p0 = 0, p1 = 0, p2 = 0, p3 = 0;
    int* op = idx_out + (((size_t)b * NPTS + qb + t) << 4);
    for (int r = 0; r < 16; ++r) {
      const float d0 = od[base + p0];
      const float d1 = od[base + 16 + p1];
      const float d2 = od[base + 32 + p2];
      const float d3 = od[base + 48 + p3];
      int bw = 0; float bd = d0;
      if (d1 < bd) { bd = d1; bw = 1; }
      if (d2 < bd) { bd = d2; bw = 2; }
      if (d3 < bd) { bd = d3; bw = 3; }
      const unsigned short bi = (bw == 0) ? oi[base + p0]
                              : (bw == 1) ? oi[base + 16 + p1]
                              : (bw == 2) ? oi[base + 32 + p2]
                                          : oi[base + 48 + p3];
      op[r] = (int)bi;
      p0 += (bw == 0); p1 += (bw == 1); p2 += (bw == 2); p3 += (bw == 3);
    }
  }
}

// ---------------- K2: fused layer1(swish) -> f16 MFMA layer2 -> maxpool ----------------
// LDS is FRAGMENT-MAJOR: 16B chunk g=(kt*128+row)*4+kgr at byte g*16.
// Staging: thread t -> row=t>>2, kgr=t&3; per kt one ds_write_b128, wave writes are
// lane-linear (1024B contiguous) -> conflict-free. MFMA reads: per-lane base
// (ln15*4+kgr)*16 + uniform imm offset (kt*8192+qi*1024) -> conflict-free.
// (R3: row-major stride-400B layout had 8-way conflicts on both sides: 3.9M conflicts.)
__global__ __launch_bounds__(512) void mlp_kernel(const float* __restrict__ pts,
                                                  const int* __restrict__ idx,
                                                  const float* __restrict__ W1,
                                                  const float* __restrict__ b1,
                                                  const _Float16* __restrict__ W2T,
                                                  const float* __restrict__ b2,
                                                  float* __restrict__ out) {
  __shared__ _Float16 sA[24576];   // 48 KB

  const int bid = blockIdx.x;
  const int b   = bid >> 9;
  const int qb  = (bid & 511) << 3;
  const float* P = pts + (size_t)b * NPTS * 3;
  const int t = threadIdx.x;

  // ---- stage A = f16(swish(f @ W1 + b1)) ----
  {
    const int row = t >> 2;          // 0..127
    const int kg  = t & 3;
    const int ql  = row >> 4;
    const int kk  = row & 15;
    const int qq  = qb + ql;
    const int nb  = idx[(((size_t)b * NPTS + qq) << 4) + kk];
    const float pqx = P[qq * 3 + 0], pqy = P[qq * 3 + 1], pqz = P[qq * 3 + 2];
    float f[6];
    f[0] = P[nb * 3 + 0] - pqx;
    f[1] = P[nb * 3 + 1] - pqy;
    f[2] = P[nb * 3 + 2] - pqz;
    f[3] = pqx; f[4] = pqy; f[5] = pqz;
#pragma unroll
    for (int kt = 0; kt < 6; ++kt) {
      const int h0 = kt * 32 + kg * 8;
      f32x4 a0 = *(const f32x4*)(b1 + h0);
      f32x4 a1 = *(const f32x4*)(b1 + h0 + 4);
#pragma unroll
      for (int in = 0; in < 6; ++in) {
        const f32x4 w0 = *(const f32x4*)(W1 + in * HDIM + h0);
        const f32x4 w1 = *(const f32x4*)(W1 + in * HDIM + h0 + 4);
        a0 += f[in] * w0;
        a1 += f[in] * w1;
      }
      f16x8 v;
#pragma unroll
      for (int j = 0; j < 4; ++j) {
        const float s0 = a0[j] * __builtin_amdgcn_rcpf(1.0f + __expf(-a0[j]));
        const float s1 = a1[j] * __builtin_amdgcn_rcpf(1.0f + __expf(-a1[j]));
        v[j]     = (_Float16)s0;
        v[j + 4] = (_Float16)s1;
      }
      *(f16x8*)(sA + ((kt * 128 + row) * 4 + kg) * 8) = v;
    }
  }
  __syncthreads();

  // ---- MFMA phase ----
  const int lane = t & 63;
  const int wv   = t >> 6;
  const int ln15 = lane & 15;
  const int kgr  = lane >> 4;
  const _Float16* aptr = sA + (ln15 * 4 + kgr) * 8;

  for (int ct = wv; ct < 24; ct += 8) {
    const int c = ct * 16 + ln15;
    f16x8 bfr[6];
#pragma unroll
    for (int kt = 0; kt < 6; ++kt)
      bfr[kt] = *(const f16x8*)(W2T + (size_t)c * HDIM + kt * 32 + kgr * 8);

    f32x4 acc[8];
#pragma unroll
    for (int qi = 0; qi < 8; ++qi)
#pragma unroll
      for (int e = 0; e < 4; ++e) acc[qi][e] = 0.0f;

#pragma unroll
    for (int kt = 0; kt < 6; ++kt) {
#pragma unroll
      for (int qi = 0; qi < 8; ++qi) {
        const f16x8 af = *(const f16x8*)(aptr + (kt * 128 + qi * 16) * 32);
        acc[qi] = __builtin_amdgcn_mfma_f32_16x16x32_f16(af, bfr[kt], acc[qi], 0, 0, 0);
      }
    }

    const float bb = b2[c];
#pragma unroll
    for (int qi = 0; qi < 8; ++qi) {
      // C/D: col=lane&15 (=channel c), row=(lane>>4)*4+reg (=neighbor k) -> max over rows
      float m = fmaxf(fmaxf(acc[qi][0], acc[qi][1]), fmaxf(acc[qi][2], acc[qi][3]));
      m = fmaxf(m, __shfl_xor(m, 16));
      m = fmaxf(m, __shfl_xor(m, 32));
      if (lane < 16)
        out[((size_t)b * NPTS + qb + qi) * CDIM + c] = m + bb;
    }
  }
}

extern "C" void kernel_launch(void* const* d_in, const int* in_sizes, int n_in,
                              void* d_out, int out_size, void* d_ws, size_t ws_size,
                              hipStream_t stream) {
  const float* point = (const float*)d_in[0];
  const float* W1    = (const float*)d_in[1];
  const float* b1    = (const float*)d_in[2];
  const float* W2    = (const float*)d_in[3];
  const float* b2    = (const float*)d_in[4];

  int*      idx_ws = (int*)d_ws;
  _Float16* W2T    = (_Float16*)((char*)d_ws + (1 << 20));

  prep_w2<<<(HDIM * CDIM + 255) / 256, 256, 0, stream>>>(W2, W2T);
  knn_kernel<<<512, 512, 0, stream>>>(point, idx_ws);
  mlp_kernel<<<NBATCH * 512, 512, 0, stream>>>(point, idx_ws, W1, b1, W2T, b2, (float*)d_out);
}